// Round 13
// baseline (349.565 us; speedup 1.0000x reference)
//
#include <hip/hip_runtime.h>
#include <math.h>

#define M_PTS 8192
#define MK    131072   // M_PTS*16
// WORKSPACE: nidx 512KB @0, stats 8KB @524288, wl_bf16 160KB @532480, pos4 128KB @696320 -> 824320 B.
// d_out (8192x256 f32 = 8MB) doubles as t-chain scratch: t1act -> t2act -> t3 -> final output.
// SESSION RULE (R1/R5/R10): never trade occupancy for a memory-pattern fix in these
// latency-bound VALU kernels -- resident waves/CU is the dominant term.

typedef __attribute__((ext_vector_type(8))) short bf16x8;
typedef __attribute__((ext_vector_type(4))) float f32x4;
typedef __fp16 half2v __attribute__((ext_vector_type(2)));
union H2U { half2v h; unsigned u; };

__device__ __forceinline__ float elu(float v){ return v > 0.f ? v : __expf(v)-1.0f; }

__device__ __forceinline__ unsigned cvt_pk_bf16(float lo, float hi){
  unsigned r;
  asm("v_cvt_pk_bf16_f32 %0, %1, %2" : "=v"(r) : "v"(lo), "v"(hi));
  return r;
}
__device__ __forceinline__ unsigned short f2bf(float v){
  unsigned u = __float_as_uint(v);
  return (unsigned short)((u + 0x7FFFu + ((u>>16)&1u)) >> 16);
}
__device__ __forceinline__ unsigned pk_min_u16(unsigned a, unsigned b){
  unsigned r; asm("v_pk_min_u16 %0, %1, %2" : "=v"(r) : "v"(a), "v"(b)); return r;
}
__device__ __forceinline__ unsigned pk_max_u16(unsigned a, unsigned b){
  unsigned r; asm("v_pk_max_u16 %0, %1, %2" : "=v"(r) : "v"(a), "v"(b)); return r;
}

__device__ __forceinline__ unsigned distkey(float4 c, float qx, float qy, float qz, float d2q){
  #pragma clang fp contract(off)
  float dot  = __builtin_fmaf(c.z, qz, __builtin_fmaf(c.y, qy, __builtin_fmaf(c.x, qx, 0.0f)));
  float A    = d2q + c.w;
  float B    = 2.0f * dot;
  float dist = A - B;
  unsigned u = __float_as_uint(dist);
  return u ^ ((unsigned)((int)u >> 31) | 0x80000000u);
}

// ---------------- knn: phase 1 per-query insertion (R7-verbatim) + TRANSPOSED phase 2 ----------------
// Phase 2: wave wv reads only tile sub-slice [wv*128, wv*128+128) (2 b128/lane/round, was 16)
// and tests those cands against ALL 8 queries (coords+thresholds in LDS). Hit slots via
// per-query LDS atomic counter; exact u32 keys + exact final sort unchanged -> nidx identical
// whenever cnt<=64 (typical ~18; >64 truncation risk unchanged vs scan-order fill).
__global__ __launch_bounds__(512) void knn_kernel(const float* __restrict__ pos,
                                                  int* __restrict__ nidx,
                                                  float* __restrict__ st,
                                                  float4* __restrict__ pos4){
  __shared__ float4 cand[1024];
  __shared__ unsigned long long hits[8][64];
  __shared__ float4 qS[8];
  __shared__ float  thrS[8];
  __shared__ int    cntS[8];
  int tid  = threadIdx.x;
  int lane = tid & 63;
  int wv   = tid >> 6;
  int q    = blockIdx.x*8 + wv;
  if (blockIdx.x == 0){
    for (int i = tid; i < 2048; i += 512) st[i] = 0.f;
  }
  float qx = pos[3*q], qy = pos[3*q+1], qz = pos[3*q+2];
  float d2q;
  {
    #pragma clang fp contract(off)
    d2q = (qx*qx + qy*qy) + qz*qz;
  }
  if (tid < 8) cntS[tid] = 0;

  unsigned ka[8];
  #pragma unroll
  for (int s=0;s<8;s++) ka[s] = 0xFFFFFFFFu;

  for (int base = 0; base < M_PTS; base += 1024){
    for (int t = tid; t < 1024; t += 512){
      #pragma clang fp contract(off)
      int j = base + t;
      float x = pos[3*j], y = pos[3*j+1], z = pos[3*j+2];
      float d2v = (x*x + y*y) + z*z;
      float4 c = make_float4(x,y,z,d2v);
      cand[t] = c;
      if (pos4 && blockIdx.x == (base >> 10)) pos4[j] = c;   // blocks 0..7 publish pos4
    }
    __syncthreads();
    #pragma unroll
    for (int k=0; k<8; k++){
      float4 c0 = cand[lane + k*128];
      float4 c1 = cand[lane + 64 + k*128];
      float dotA = c0.x*qx + c0.y*qy + c0.z*qz;
      float dotB = c1.x*qx + c1.y*qy + c1.z*qz;
      float dA = fmaxf((d2q + c0.w) - 2.0f*dotA, 0.f);
      float dB = fmaxf((d2q + c1.w) - 2.0f*dotB, 0.f);
      H2U pu; pu.h = __builtin_amdgcn_cvt_pkrtz(dA, dB);
      unsigned v = pu.u;
      #pragma unroll
      for (int s=0;s<8;s++){
        unsigned mn = pk_min_u16(v, ka[s]);
        unsigned mx = pk_max_u16(v, ka[s]);
        ka[s] = mn; v = mx;
      }
    }
    __syncthreads();
  }

  unsigned lo[8], hi[8];
  #pragma unroll
  for (int s=0;s<8;s++){ lo[s] = ka[s] & 0xFFFFu; hi[s] = ka[s] >> 16; }
  unsigned t16 = 0xFFFFu;
  for (int r=0; r<16; r++){
    unsigned head = min(lo[0], hi[0]);
    unsigned best = head;
    #pragma unroll
    for (int off=32; off>0; off>>=1){
      unsigned o = __shfl_xor(best, off, 64);
      best = min(best, o);
    }
    bool adv = (head == best);
    bool fromLo = lo[0] <= hi[0];
    bool aL = adv && fromLo;
    bool aH = adv && !fromLo;
    #pragma unroll
    for (int s=0;s<7;s++){
      lo[s] = aL ? lo[s+1] : lo[s];
      hi[s] = aH ? hi[s+1] : hi[s];
    }
    lo[7] = aL ? 0xFFFFu : lo[7];
    hi[7] = aH ? 0xFFFFu : hi[7];
    t16 = best;
  }
  unsigned tu = min(t16 + 2u, 0x7C00u);
  float thrF;
  asm("v_cvt_f32_f16 %0, %1" : "=v"(thrF) : "v"(tu));
  if (lane == 0){
    qS[wv]   = make_float4(qx, qy, qz, d2q);
    thrS[wv] = thrF;
  }
  // visibility of qS/thrS/cntS covered by the first __syncthreads() in the phase-2 loop

  // phase 2 (transposed): wave wv scans sub-slice [wv*128, wv*128+128) for all 8 queries
  for (int base = 0; base < M_PTS; base += 1024){
    for (int t = tid; t < 1024; t += 512){
      #pragma clang fp contract(off)
      int j = base + t;
      float x = pos[3*j], y = pos[3*j+1], z = pos[3*j+2];
      float d2v = (x*x + y*y) + z*z;
      cand[t] = make_float4(x,y,z,d2v);
    }
    __syncthreads();
    float4 c0 = cand[wv*128 + lane];
    float4 c1 = cand[wv*128 + 64 + lane];
    int j0 = base + wv*128 + lane;
    int j1 = j0 + 64;
    #pragma unroll
    for (int qq = 0; qq < 8; qq++){
      float4 qv = qS[qq];
      float  thr = thrS[qq];
      {
        float dot = c0.x*qv.x + c0.y*qv.y + c0.z*qv.z;
        bool hit = ((qv.w + c0.w) - 2.0f*dot) <= thr;
        unsigned long long m = __ballot(hit);
        if (m){
          unsigned u = distkey(c0, qv.x, qv.y, qv.z, qv.w);
          int bs;
          if (lane == 0) bs = atomicAdd(&cntS[qq], (int)__popcll(m));
          bs = __shfl(bs, 0, 64);
          if (hit){
            int slot = bs + __popcll(m & ((1ull<<lane)-1ull));
            if (slot < 64) hits[qq][slot] = ((unsigned long long)u << 32) | (unsigned)j0;
          }
        }
      }
      {
        float dot = c1.x*qv.x + c1.y*qv.y + c1.z*qv.z;
        bool hit = ((qv.w + c1.w) - 2.0f*dot) <= thr;
        unsigned long long m = __ballot(hit);
        if (m){
          unsigned u = distkey(c1, qv.x, qv.y, qv.z, qv.w);
          int bs;
          if (lane == 0) bs = atomicAdd(&cntS[qq], (int)__popcll(m));
          bs = __shfl(bs, 0, 64);
          if (hit){
            int slot = bs + __popcll(m & ((1ull<<lane)-1ull));
            if (slot < 64) hits[qq][slot] = ((unsigned long long)u << 32) | (unsigned)j1;
          }
        }
      }
    }
    __syncthreads();
  }

  int cc = min(cntS[wv], 64);
  unsigned long long mine = (lane < cc) ? hits[wv][lane] : ~0ull;
  for (int r=0; r<16; r++){
    unsigned long long best = mine;
    #pragma unroll
    for (int off=32; off>0; off>>=1){
      unsigned long long o = __shfl_xor(best, off, 64);
      best = (o < best) ? o : best;
    }
    if (mine == best) mine = ~0ull;
    if (lane == 0) nidx[q*16 + r] = (int)(unsigned)best;
  }
}

// ---------------- stats_a: [0,512) s1; [512,1536) t1act; [1536,1576) wl -> bf16 frag-swizzle ----------------
__global__ __launch_bounds__(256) void stats_a_kernel(const float* __restrict__ pos,
    const float4* __restrict__ pos4,
    const int* __restrict__ nidx,
    const float* __restrict__ w1a, const float* __restrict__ b1a,
    const float* __restrict__ w2,  const float* __restrict__ b2,
    const float* __restrict__ wl,  unsigned short* __restrict__ wlbf,
    float* __restrict__ tact,
    float* __restrict__ s1, float* __restrict__ s3){
  int tid = threadIdx.x;
  if (blockIdx.x < 512){
    __shared__ float relS[256][3];
    __shared__ float red[8][64];
    int r = blockIdx.x*256 + tid;
    int m = r >> 4;
    int j = nidx[r];
    if (pos4){
      float4 pj = pos4[j], pm = pos4[m];
      relS[tid][0] = pj.x-pm.x; relS[tid][1] = pj.y-pm.y; relS[tid][2] = pj.z-pm.z;
    } else {
      relS[tid][0] = pos[3*j  ]-pos[3*m  ];
      relS[tid][1] = pos[3*j+1]-pos[3*m+1];
      relS[tid][2] = pos[3*j+2]-pos[3*m+2];
    }
    __syncthreads();
    int c = tid & 31, g = tid >> 5;
    float w0=w1a[c], w1v=w1a[32+c], w2v=w1a[64+c], b=b1a[c];
    float s=0.f, q=0.f;
    for (int rr=g*32; rr<g*32+32; rr++){
      float h = elu(b + relS[rr][0]*w0 + relS[rr][1]*w1v + relS[rr][2]*w2v);
      s += h; q += h*h;
    }
    red[g][c]=s; red[g][32+c]=q;
    __syncthreads();
    if (tid < 64){
      float a=0.f;
      #pragma unroll
      for (int gg=0;gg<8;gg++) a += red[gg][tid];
      atomicAdd(&s1[tid], a);
    }
  } else if (blockIdx.x < 1536){
    __shared__ float relf[8][48];
    int m0 = (blockIdx.x-512)*8;
    if (pos4){
      for (int f = tid; f < 8*16; f += 256){
        int p = f >> 4, k = f & 15;
        int j = nidx[(m0+p)*16 + k];
        float4 pj = pos4[j], pm = pos4[m0+p];
        relf[p][k*3+0] = pj.x-pm.x;
        relf[p][k*3+1] = pj.y-pm.y;
        relf[p][k*3+2] = pj.z-pm.z;
      }
    } else {
      for (int f = tid; f < 8*48; f += 256){
        int p = f/48, kd = f%48, k = kd/3, d = kd%3;
        int j = nidx[(m0+p)*16 + k];
        relf[p][kd] = pos[3*j+d] - pos[3*(m0+p)+d];
      }
    }
    __syncthreads();
    float acc[8];
    #pragma unroll
    for (int p=0;p<8;p++) acc[p] = b2[tid];
    for (int kk=0; kk<48; kk++){
      float w = w2[kk*256 + tid];
      #pragma unroll
      for (int p=0;p<8;p++) acc[p] += relf[p][kk]*w;
    }
    float s=0.f, q=0.f;
    #pragma unroll
    for (int p=0;p<8;p++){
      float v = elu(acc[p]);
      s += v; q += v*v;
      tact[(size_t)(m0+p)*256 + tid] = v;
    }
    atomicAdd(&s3[tid], s); atomicAdd(&s3[256+tid], q);
  } else {
    // wl [320x256] f32 -> bf16, swizzled to MFMA B-fragment-linear order.
    int t = (blockIdx.x - 1536)*256 + tid;   // 0..10239
    int lane = t & 63;
    int fr   = t >> 6;
    int k0   = (fr >> 4)*32 + (lane >> 4)*8;
    int col  = (fr & 15)*16 + (lane & 15);
    const float* wp = wl + (size_t)k0*256 + col;
    uint4 v;
    v.x = cvt_pk_bf16(wp[0],    wp[256]);
    v.y = cvt_pk_bf16(wp[512],  wp[768]);
    v.z = cvt_pk_bf16(wp[1024], wp[1280]);
    v.w = cvt_pk_bf16(wp[1536], wp[1792]);
    ((uint4*)wlbf)[t] = v;
  }
}

// ---------------- stats_b: [0,1024) s2 (h2 stats, 128 rows/block); [1024,2048) t2act ----------------
__global__ __launch_bounds__(256) void stats_b_kernel(const float* __restrict__ pos,
    const float4* __restrict__ pos4,
    const int* __restrict__ nidx,
    const float* __restrict__ w1a, const float* __restrict__ b1a,
    const float* __restrict__ s1,  const float* __restrict__ g1a, const float* __restrict__ be1a,
    const float* __restrict__ w1b, const float* __restrict__ b1b,
    float* __restrict__ tact,
    const float* __restrict__ s3,  const float* __restrict__ g2a, const float* __restrict__ be2a,
    const float* __restrict__ wc2a,const float* __restrict__ bc2a,
    float* __restrict__ s2, float* __restrict__ s4){
  int tid = threadIdx.x;
  const float invMK = 1.f/(float)MK;
  const float invM  = 1.f/8192.f;
  if (blockIdx.x < 1024){
    __shared__ float xnS[128][33];
    __shared__ float red[8][64];
    __shared__ float muA[32], ivA[32];
    if (tid < 32){
      float mu  = s1[tid]*invMK;
      float var = s1[32+tid]*invMK - mu*mu;
      muA[tid] = mu; ivA[tid] = rsqrtf(var+1e-5f)*g1a[tid];
    }
    __syncthreads();
    {
      int rl = tid >> 1;                    // 0..127
      int r  = blockIdx.x*128 + rl;
      int m = r >> 4;
      int j = nidx[r];
      float rx, ry, rz;
      if (pos4){
        float4 pj = pos4[j], pm = pos4[m];
        rx = pj.x-pm.x; ry = pj.y-pm.y; rz = pj.z-pm.z;
      } else {
        rx = pos[3*j]-pos[3*m]; ry = pos[3*j+1]-pos[3*m+1]; rz = pos[3*j+2]-pos[3*m+2];
      }
      int c0 = (tid & 1)*16;
      #pragma unroll
      for (int u=0; u<16; u++){
        int cc = c0 + u;
        float h = elu(b1a[cc] + rx*w1a[cc] + ry*w1a[32+cc] + rz*w1a[64+cc]);
        xnS[rl][cc] = (h-muA[cc])*ivA[cc] + be1a[cc];
      }
    }
    __syncthreads();
    int o = tid & 31, g = tid >> 5;
    float wcol[32];
    #pragma unroll
    for (int cc=0;cc<32;cc++) wcol[cc] = w1b[cc*32+o];
    float bo = b1b[o], s=0.f, q=0.f;
    for (int rr=g*16; rr<g*16+16; rr++){
      float a = bo;
      #pragma unroll
      for (int cc=0;cc<32;cc++) a += xnS[rr][cc]*wcol[cc];
      float v = elu(a);
      s += v; q += v*v;
    }
    red[g][o]=s; red[g][32+o]=q;
    __syncthreads();
    if (tid < 64){
      float a=0.f;
      #pragma unroll
      for (int gg=0;gg<8;gg++) a += red[gg][tid];
      atomicAdd(&s2[tid], a);
    }
  } else {
    __shared__ float tn[8][256];
    int m0 = (blockIdx.x-1024)*8;
    float mu3  = s3[tid]*invM;
    float var3 = s3[256+tid]*invM - mu3*mu3;
    float i3   = rsqrtf(var3+1e-5f)*g2a[tid];
    float bb3  = be2a[tid];
    float tv[8];
    #pragma unroll
    for (int p=0;p<8;p++) tv[p] = tact[(size_t)(m0+p)*256 + tid];
    #pragma unroll
    for (int p=0;p<8;p++) tn[p][tid] = (tv[p]-mu3)*i3 + bb3;
    __syncthreads();
    int c = tid >> 4;
    float wreg[16];
    const float4* wv4 = (const float4*)(wc2a + tid*16);
    #pragma unroll
    for (int v=0; v<4; v++){ float4 f = wv4[v]; wreg[4*v]=f.x; wreg[4*v+1]=f.y; wreg[4*v+2]=f.z; wreg[4*v+3]=f.w; }
    float bias = bc2a[tid];
    float s=0.f, q=0.f;
    #pragma unroll
    for (int p=0;p<8;p++){
      float a2 = bias;
      #pragma unroll
      for (int l=0;l<16;l++) a2 += tn[p][c*16+l]*wreg[l];
      float v = elu(a2);
      s += v; q += v*v;
      tv[p] = v;
    }
    #pragma unroll
    for (int p=0;p<8;p++) tact[(size_t)(m0+p)*256 + tid] = tv[p];
    atomicAdd(&s4[tid], s); atomicAdd(&s4[256+tid], q);
  }
}

// ---------------- t3_stats: t3 = gconv2(BN(t2act)) (no elu) -> d_out + s5 ----------------
__global__ __launch_bounds__(256) void t3_stats_kernel(
    float* __restrict__ tact,
    const float* __restrict__ s4, const float* __restrict__ g2b, const float* __restrict__ be2b,
    const float* __restrict__ wc2b, const float* __restrict__ bc2b, float* __restrict__ s5){
  __shared__ float tn2[8][256];
  int m0 = blockIdx.x*8, tid = threadIdx.x;
  const float invM = 1.f/8192.f;
  float mu4  = s4[tid]*invM;
  float var4 = s4[256+tid]*invM - mu4*mu4;
  float i4   = rsqrtf(var4+1e-5f)*g2b[tid];
  float bb4  = be2b[tid];
  float tv[8];
  #pragma unroll
  for (int p=0;p<8;p++) tv[p] = tact[(size_t)(m0+p)*256 + tid];
  #pragma unroll
  for (int p=0;p<8;p++) tn2[p][tid] = (tv[p]-mu4)*i4 + bb4;
  __syncthreads();
  int c = tid >> 4;
  float w2reg[16];
  { const float4* wv4 = (const float4*)(wc2b + tid*16);
    #pragma unroll
    for (int v=0; v<4; v++){ float4 f = wv4[v]; w2reg[4*v]=f.x; w2reg[4*v+1]=f.y; w2reg[4*v+2]=f.z; w2reg[4*v+3]=f.w; } }
  float bias2 = bc2b[tid];
  float s=0.f, q=0.f;
  #pragma unroll
  for (int p=0;p<8;p++){
    float a3 = bias2;
    #pragma unroll
    for (int l=0;l<16;l++) a3 += tn2[p][c*16+l]*w2reg[l];
    s += a3; q += a3*a3;
    tv[p] = a3;
  }
  #pragma unroll
  for (int p=0;p<8;p++) tact[(size_t)(m0+p)*256 + tid] = tv[p];
  atomicAdd(&s5[tid], s); atomicAdd(&s5[256+tid], q);
}

// ---------------- final (MFMA path, R9-verbatim): PF=4, 19KB LDS, 8 blocks/CU ----------------
#define PFM 4
__global__ __launch_bounds__(256) void final_mfma_kernel(
    const float* __restrict__ x, const float* __restrict__ pos,
    const float4* __restrict__ pos4, const int* __restrict__ nidx,
    const float* __restrict__ w1a, const float* __restrict__ b1a,
    const float* __restrict__ g1a, const float* __restrict__ be1a,
    const float* __restrict__ w1b, const float* __restrict__ b1b,
    const float* __restrict__ g1b, const float* __restrict__ be1b,
    const float* __restrict__ g2c, const float* __restrict__ be2c,
    const float* __restrict__ wcd, const float* __restrict__ bcd,
    const unsigned short* __restrict__ wlbf, const float* __restrict__ bl,
    const float* __restrict__ st,
    float* __restrict__ out){
  __shared__ float tA[PFM][256];                // BN(t3), f32 (4KB)
  __shared__ unsigned short xs[PFM*32*17];      // h2n bf16 (4.4KB)
  __shared__ unsigned short yh[16][328];        // yy bf16; rows 4..15 zero (MFMA M-pad)
  __shared__ int   sidx[PFM*16];
  __shared__ float mu1[32], i1g[32], mu2[32], i2g[32];
  int tid = threadIdx.x;
  int m0  = blockIdx.x*PFM;
  const float invMK = 1.f/(float)MK;
  const float invM  = 1.f/8192.f;

  if (tid < PFM*16) sidx[tid] = nidx[m0*16 + tid];
  if (tid < 32){
    float mu  = st[tid]*invMK;
    float var = st[32+tid]*invMK - mu*mu;
    mu1[tid] = mu; i1g[tid] = rsqrtf(var+1e-5f)*g1a[tid];
    float mu_2  = st[64+tid]*invMK;
    float var_2 = st[96+tid]*invMK - mu_2*mu_2;
    mu2[tid] = mu_2; i2g[tid] = rsqrtf(var_2+1e-5f)*g1b[tid];
  }
  {
    unsigned short* yz = &yh[PFM][0];
    for (int i = tid; i < (16-PFM)*328; i += 256) yz[i] = 0;
  }
  {
    float mu5 = st[1152+tid]*invM, var5 = st[1408+tid]*invM - mu5*mu5;
    float i5 = rsqrtf(var5+1e-5f)*g2c[tid], bb5 = be2c[tid];
    #pragma unroll
    for (int p=0;p<PFM;p++){
      float v = out[(size_t)(m0+p)*256 + tid];
      tA[p][tid] = (v-mu5)*i5 + bb5;
    }
  }
  __syncthreads();

  // phase A: h1->BN->h2->BN for 64 neighbor rows (4 threads/row)
  {
    int row = tid >> 2;
    int p = row >> 4, k = row & 15;
    int q8 = (tid & 3)*8;
    int m = m0 + p;
    int j = sidx[row];
    float rx, ry, rz;
    if (pos4){
      float4 pj = pos4[j], pm = pos4[m];
      rx = pj.x-pm.x; ry = pj.y-pm.y; rz = pj.z-pm.z;
    } else {
      rx = pos[3*j]-pos[3*m]; ry = pos[3*j+1]-pos[3*m+1]; rz = pos[3*j+2]-pos[3*m+2];
    }
    float xn[32];
    #pragma unroll
    for (int cc=0; cc<32; cc++){
      float h = elu(b1a[cc] + rx*w1a[cc] + ry*w1a[32+cc] + rz*w1a[64+cc]);
      xn[cc] = (h-mu1[cc])*i1g[cc] + be1a[cc];
    }
    #pragma unroll
    for (int oo=0; oo<8; oo++){
      int o = q8 + oo;
      float a = b1b[o];
      #pragma unroll
      for (int cc=0; cc<32; cc++) a += xn[cc]*w1b[cc*32+o];
      float h2v = elu(a);
      xs[(p*32 + o)*17 + k] = f2bf((h2v-mu2[o])*i2g[o] + be1b[o]);
    }
  }
  __syncthreads();

  // phase B: X-transform + depthwise -> yy (bf16 into yh); x gathered direct (L2-resident, 4MB)
  for (int pair = tid; pair < PFM*160; pair += 256){
    int p = pair / 160, cch = pair % 160;
    float av[16];
    if (cch < 32){
      #pragma unroll
      for (int k16=0;k16<16;k16++)
        av[k16] = __uint_as_float((unsigned)xs[(p*32+cch)*17 + k16] << 16);
    } else {
      #pragma unroll
      for (int k16=0;k16<16;k16++) av[k16] = x[(size_t)sidx[p*16+k16]*128 + (cch-32)];
    }
    float xt[16];
    #pragma unroll
    for (int j16=0;j16<16;j16++) xt[j16]=0.f;
    #pragma unroll
    for (int k16=0;k16<16;k16++){
      float a = av[k16];
      #pragma unroll
      for (int j16=0;j16<16;j16++) xt[j16] += a*tA[p][k16*16+j16];
    }
    float y0 = bcd[cch*2], y1 = bcd[cch*2+1];
    #pragma unroll
    for (int l=0;l<16;l++){
      y0 += xt[l]*wcd[cch*32 + l];
      y1 += xt[l]*wcd[cch*32 + 16 + l];
    }
    *(unsigned*)&yh[p][cch*2] = cvt_pk_bf16(y0, y1);
  }
  __syncthreads();

  // phase C: out[4x256] = yy[4(->16)x320] @ wl[320x256] + bl via MFMA 16x16x32 bf16.
  {
    int lane = tid & 63;
    int wvi  = tid >> 6;
    int lrow = lane & 15;
    int lgrp = lane >> 4;
    const bf16x8* wb = (const bf16x8*)wlbf;
    f32x4 acc[4];
    #pragma unroll
    for (int nt=0; nt<4; ++nt) acc[nt] = (f32x4){0.f,0.f,0.f,0.f};
    #pragma unroll 1
    for (int kt = 0; kt < 10; ++kt){
      bf16x8 ah = *(const bf16x8*)&yh[lrow][kt*32 + lgrp*8];
      #pragma unroll
      for (int nt = 0; nt < 4; ++nt){
        bf16x8 bh = wb[(size_t)((kt*16 + wvi*4 + nt)*64) + lane];
        acc[nt] = __builtin_amdgcn_mfma_f32_16x16x32_bf16(ah, bh, acc[nt], 0, 0, 0);
      }
    }
    if (lgrp == 0){
      #pragma unroll
      for (int nt=0; nt<4; ++nt){
        int col = wvi*64 + nt*16 + lrow;
        float bv = bl[col];
        #pragma unroll
        for (int r=0;r<4;r++){
          int orow = r;                        // D row = (lane>>4)*4 + reg; rows 0..3 live (m89-verified)
          out[(size_t)(m0+orow)*256 + col] = acc[nt][r] + bv;
        }
      }
    }
  }
}

// ---------------- final (legacy fallback, verbatim R3): PF=4, serial phase C ----------------
#define PF 4
__global__ __launch_bounds__(256) void final_kernel(
    const float* __restrict__ x, const float* __restrict__ pos, const int* __restrict__ nidx,
    const float* __restrict__ w1a, const float* __restrict__ b1a,
    const float* __restrict__ g1a, const float* __restrict__ be1a,
    const float* __restrict__ w1b, const float* __restrict__ b1b,
    const float* __restrict__ g1b, const float* __restrict__ be1b,
    const float* __restrict__ g2c, const float* __restrict__ be2c,
    const float* __restrict__ wcd, const float* __restrict__ bcd,
    const float* __restrict__ wl,  const float* __restrict__ bl,
    const float* __restrict__ st,
    float* __restrict__ out){
  __shared__ float tA[PF][256];
  __shared__ float xs[PF*32*17];
  __shared__ float yy[PF][320];
  __shared__ int   sidx[PF*16];
  __shared__ float mu1[32], i1g[32], mu2[32], i2g[32];
  int tid = threadIdx.x;
  int m0  = blockIdx.x*PF;
  const float invMK = 1.f/(float)MK;
  const float invM  = 1.f/8192.f;

  if (tid < PF*16) sidx[tid] = nidx[m0*16 + tid];
  if (tid < 32){
    float mu  = st[tid]*invMK;
    float var = st[32+tid]*invMK - mu*mu;
    mu1[tid] = mu; i1g[tid] = rsqrtf(var+1e-5f)*g1a[tid];
    float mu_2  = st[64+tid]*invMK;
    float var_2 = st[96+tid]*invMK - mu_2*mu_2;
    mu2[tid] = mu_2; i2g[tid] = rsqrtf(var_2+1e-5f)*g1b[tid];
  }
  {
    float mu5 = st[1152+tid]*invM, var5 = st[1408+tid]*invM - mu5*mu5;
    float i5 = rsqrtf(var5+1e-5f)*g2c[tid], bb5 = be2c[tid];
    #pragma unroll
    for (int p=0;p<PF;p++){
      float v = out[(size_t)(m0+p)*256 + tid];
      tA[p][tid] = (v-mu5)*i5 + bb5;
    }
  }
  __syncthreads();

  {
    int row = tid >> 2;
    int p = row >> 4, k = row & 15;
    int q8 = (tid & 3)*8;
    int m = m0 + p;
    int j = sidx[p*16 + k];
    float rx = pos[3*j]-pos[3*m], ry = pos[3*j+1]-pos[3*m+1], rz = pos[3*j+2]-pos[3*m+2];
    float xn[32];
    #pragma unroll
    for (int cc=0; cc<32; cc++){
      float h = elu(b1a[cc] + rx*w1a[cc] + ry*w1a[32+cc] + rz*w1a[64+cc]);
      xn[cc] = (h-mu1[cc])*i1g[cc] + be1a[cc];
    }
    #pragma unroll
    for (int oo=0; oo<8; oo++){
      int o = q8 + oo;
      float a = b1b[o];
      #pragma unroll
      for (int cc=0; cc<32; cc++) a += xn[cc]*w1b[cc*32+o];
      float h2v = elu(a);
      xs[(p*32 + o)*17 + k] = (h2v-mu2[o])*i2g[o] + be1b[o];
    }
  }
  __syncthreads();

  for (int pair = tid; pair < PF*160; pair += 256){
    int p = pair / 160, cch = pair % 160;
    float av[16];
    if (cch < 32){
      #pragma unroll
      for (int k16=0;k16<16;k16++) av[k16] = xs[(p*32+cch)*17 + k16];
    } else {
      #pragma unroll
      for (int k16=0;k16<16;k16++) av[k16] = x[(size_t)sidx[p*16+k16]*128 + (cch-32)];
    }
    float xt[16];
    #pragma unroll
    for (int j16=0;j16<16;j16++) xt[j16]=0.f;
    #pragma unroll
    for (int k16=0;k16<16;k16++){
      float a = av[k16];
      #pragma unroll
      for (int j16=0;j16<16;j16++) xt[j16] += a*tA[p][k16*16+j16];
    }
    float y0 = bcd[cch*2], y1 = bcd[cch*2+1];
    #pragma unroll
    for (int l=0;l<16;l++){
      y0 += xt[l]*wcd[cch*32 + l];
      y1 += xt[l]*wcd[cch*32 + 16 + l];
    }
    yy[p][cch*2] = y0; yy[p][cch*2+1] = y1;
  }
  __syncthreads();

  float accO[PF];
  #pragma unroll
  for (int p=0;p<PF;p++) accO[p] = bl[tid];
  for (int q=0;q<320;q++){
    float w = wl[q*256 + tid];
    #pragma unroll
    for (int p=0;p<PF;p++) accO[p] += yy[p][q]*w;
  }
  #pragma unroll
  for (int p=0;p<PF;p++) out[(size_t)(m0+p)*256 + tid] = accO[p];
}

extern "C" void kernel_launch(void* const* d_in, const int* in_sizes, int n_in,
                              void* d_out, int out_size, void* d_ws, size_t ws_size,
                              hipStream_t stream){
  const float* x    = (const float*)d_in[0];
  const float* pos  = (const float*)d_in[1];
  const float* w1a  = (const float*)d_in[2];
  const float* b1a  = (const float*)d_in[3];
  const float* g1a  = (const float*)d_in[4];
  const float* be1a = (const float*)d_in[5];
  const float* w1b  = (const float*)d_in[6];
  const float* b1b  = (const float*)d_in[7];
  const float* g1b  = (const float*)d_in[8];
  const float* be1b = (const float*)d_in[9];
  const float* w2   = (const float*)d_in[10];
  const float* b2   = (const float*)d_in[11];
  const float* g2a  = (const float*)d_in[12];
  const float* be2a = (const float*)d_in[13];
  const float* wc2a = (const float*)d_in[14];
  const float* bc2a = (const float*)d_in[15];
  const float* g2b  = (const float*)d_in[16];
  const float* be2b = (const float*)d_in[17];
  const float* wc2b = (const float*)d_in[18];
  const float* bc2b = (const float*)d_in[19];
  const float* g2c  = (const float*)d_in[20];
  const float* be2c = (const float*)d_in[21];
  const float* wcd  = (const float*)d_in[22];
  const float* bcd  = (const float*)d_in[23];
  const float* wl   = (const float*)d_in[24];
  const float* bl   = (const float*)d_in[25];
  float* out = (float*)d_out;

  char* ws = (char*)d_ws;
  int*   nidx = (int*)(ws + 0);          // 512 KB
  float* st   = (float*)(ws + 524288);   // 8 KB (s1@0, s2@64, s3@128, s4@640, s5@1152)
  float* s1 = st;
  float* s2 = st + 64;
  float* s3 = st + 128;
  float* s4 = st + 640;
  float* s5 = st + 1152;
  bool big  = ws_size >= (size_t)696320;
  bool big2 = ws_size >= (size_t)824320;
  unsigned short* wlbf = big  ? (unsigned short*)(ws + 532480) : (unsigned short*)0;  // 160 KB
  float4*         pos4 = big2 ? (float4*)(ws + 696320)         : (float4*)0;          // 128 KB

  knn_kernel<<<1024,512,0,stream>>>(pos, nidx, st, pos4);
  stats_a_kernel<<<(big ? 1576 : 1536),256,0,stream>>>(pos, pos4, nidx, w1a, b1a, w2, b2,
                                                       wl, wlbf, out, s1, s3);
  stats_b_kernel<<<2048,256,0,stream>>>(pos, pos4, nidx, w1a, b1a, s1, g1a, be1a, w1b, b1b,
                                        out, s3, g2a, be2a, wc2a, bc2a, s2, s4);
  t3_stats_kernel<<<1024,256,0,stream>>>(out, s4, g2b, be2b, wc2b, bc2b, s5);
  if (big){
    final_mfma_kernel<<<2048,256,0,stream>>>(x, pos, pos4, nidx,
                                             w1a, b1a, g1a, be1a, w1b, b1b, g1b, be1b,
                                             g2c, be2c, wcd, bcd, wlbf, bl, st, out);
  } else {
    final_kernel<<<2048,256,0,stream>>>(x, pos, nidx,
                                        w1a, b1a, g1a, be1a, w1b, b1b, g1b, be1b,
                                        g2c, be2c, wcd, bcd, wl, bl, st, out);
  }
}

// Round 14
// 326.317 us; speedup vs baseline: 1.0712x; 1.0712x over previous
//
#include <hip/hip_runtime.h>
#include <math.h>

#define M_PTS 8192
#define MK    131072   // M_PTS*16
// WORKSPACE: nidx 512KB @0, stats 8KB @524288, wl_bf16 160KB @532480, pos4 128KB @696320,
//            h2cache 8MB @824320 (bf16 [131072][32], if ws allows) -> 9212928 B.
// d_out (8192x256 f32 = 8MB) doubles as t-chain scratch: t1act -> t2act -> t3 -> final output.
// SESSION RULES: (R1/R5/R10) never trade occupancy for a memory-pattern fix;
// (R5/R8/R13) knn ~86us is a structural latency floor -- stop shaving it.

typedef __attribute__((ext_vector_type(8))) short bf16x8;
typedef __attribute__((ext_vector_type(4))) float f32x4;
typedef __fp16 half2v __attribute__((ext_vector_type(2)));
union H2U { half2v h; unsigned u; };

__device__ __forceinline__ float elu(float v){ return v > 0.f ? v : __expf(v)-1.0f; }

__device__ __forceinline__ unsigned cvt_pk_bf16(float lo, float hi){
  unsigned r;
  asm("v_cvt_pk_bf16_f32 %0, %1, %2" : "=v"(r) : "v"(lo), "v"(hi));
  return r;
}
__device__ __forceinline__ unsigned short f2bf(float v){
  unsigned u = __float_as_uint(v);
  return (unsigned short)((u + 0x7FFFu + ((u>>16)&1u)) >> 16);
}
__device__ __forceinline__ unsigned pk_min_u16(unsigned a, unsigned b){
  unsigned r; asm("v_pk_min_u16 %0, %1, %2" : "=v"(r) : "v"(a), "v"(b)); return r;
}
__device__ __forceinline__ unsigned pk_max_u16(unsigned a, unsigned b){
  unsigned r; asm("v_pk_max_u16 %0, %1, %2" : "=v"(r) : "v"(a), "v"(b)); return r;
}

__device__ __forceinline__ unsigned distkey(float4 c, float qx, float qy, float qz, float d2q){
  #pragma clang fp contract(off)
  float dot  = __builtin_fmaf(c.z, qz, __builtin_fmaf(c.y, qy, __builtin_fmaf(c.x, qx, 0.0f)));
  float A    = d2q + c.w;
  float B    = 2.0f * dot;
  float dist = A - B;
  unsigned u = __float_as_uint(dist);
  return u ^ ((unsigned)((int)u >> 31) | 0x80000000u);
}

// ---------------- knn (R11-verbatim): R7 scan, grid 1024, blocks 0..7 dual-write pos4 ----------------
__global__ __launch_bounds__(512) void knn_kernel(const float* __restrict__ pos,
                                                  int* __restrict__ nidx,
                                                  float* __restrict__ st,
                                                  float4* __restrict__ pos4){
  __shared__ float4 cand[1024];
  __shared__ unsigned long long hits[8][64];
  int tid  = threadIdx.x;
  int lane = tid & 63;
  int wv   = tid >> 6;
  int q    = blockIdx.x*8 + wv;
  if (blockIdx.x == 0){
    for (int i = tid; i < 2048; i += 512) st[i] = 0.f;
  }
  float qx = pos[3*q], qy = pos[3*q+1], qz = pos[3*q+2];
  float d2q;
  {
    #pragma clang fp contract(off)
    d2q = (qx*qx + qy*qy) + qz*qz;
  }

  unsigned ka[8];
  #pragma unroll
  for (int s=0;s<8;s++) ka[s] = 0xFFFFFFFFu;

  for (int base = 0; base < M_PTS; base += 1024){
    for (int t = tid; t < 1024; t += 512){
      #pragma clang fp contract(off)
      int j = base + t;
      float x = pos[3*j], y = pos[3*j+1], z = pos[3*j+2];
      float d2v = (x*x + y*y) + z*z;
      float4 c = make_float4(x,y,z,d2v);
      cand[t] = c;
      if (pos4 && blockIdx.x == (base >> 10)) pos4[j] = c;   // blocks 0..7 publish pos4
    }
    __syncthreads();
    #pragma unroll
    for (int k=0; k<8; k++){
      float4 c0 = cand[lane + k*128];
      float4 c1 = cand[lane + 64 + k*128];
      float dotA = c0.x*qx + c0.y*qy + c0.z*qz;
      float dotB = c1.x*qx + c1.y*qy + c1.z*qz;
      float dA = fmaxf((d2q + c0.w) - 2.0f*dotA, 0.f);
      float dB = fmaxf((d2q + c1.w) - 2.0f*dotB, 0.f);
      H2U pu; pu.h = __builtin_amdgcn_cvt_pkrtz(dA, dB);
      unsigned v = pu.u;
      #pragma unroll
      for (int s=0;s<8;s++){
        unsigned mn = pk_min_u16(v, ka[s]);
        unsigned mx = pk_max_u16(v, ka[s]);
        ka[s] = mn; v = mx;
      }
    }
    __syncthreads();
  }

  unsigned lo[8], hi[8];
  #pragma unroll
  for (int s=0;s<8;s++){ lo[s] = ka[s] & 0xFFFFu; hi[s] = ka[s] >> 16; }
  unsigned t16 = 0xFFFFu;
  for (int r=0; r<16; r++){
    unsigned head = min(lo[0], hi[0]);
    unsigned best = head;
    #pragma unroll
    for (int off=32; off>0; off>>=1){
      unsigned o = __shfl_xor(best, off, 64);
      best = min(best, o);
    }
    bool adv = (head == best);
    bool fromLo = lo[0] <= hi[0];
    bool aL = adv && fromLo;
    bool aH = adv && !fromLo;
    #pragma unroll
    for (int s=0;s<7;s++){
      lo[s] = aL ? lo[s+1] : lo[s];
      hi[s] = aH ? hi[s+1] : hi[s];
    }
    lo[7] = aL ? 0xFFFFu : lo[7];
    hi[7] = aH ? 0xFFFFu : hi[7];
    t16 = best;
  }
  unsigned tu = min(t16 + 2u, 0x7C00u);
  float thrF;
  asm("v_cvt_f32_f16 %0, %1" : "=v"(thrF) : "v"(tu));

  int cnt = 0;
  for (int base = 0; base < M_PTS; base += 1024){
    for (int t = tid; t < 1024; t += 512){
      #pragma clang fp contract(off)
      int j = base + t;
      float x = pos[3*j], y = pos[3*j+1], z = pos[3*j+2];
      float d2v = (x*x + y*y) + z*z;
      cand[t] = make_float4(x,y,z,d2v);
    }
    __syncthreads();
    #pragma unroll
    for (int k=0; k<16; k++){
      int idx = lane + k*64;
      int j = base + idx;
      float4 c = cand[idx];
      float dot = c.x*qx + c.y*qy + c.z*qz;
      bool hit = ((d2q + c.w) - 2.0f*dot) <= thrF;
      unsigned long long m = __ballot(hit);
      if (m){
        unsigned u = distkey(c, qx, qy, qz, d2q);
        if (hit){
          int slot = cnt + __popcll(m & ((1ull<<lane)-1ull));
          if (slot < 64) hits[wv][slot] = ((unsigned long long)u << 32) | (unsigned)j;
        }
        cnt += (int)__popcll(m);
      }
    }
    __syncthreads();
  }

  int cc = min(cnt, 64);
  unsigned long long mine = (lane < cc) ? hits[wv][lane] : ~0ull;
  for (int r=0; r<16; r++){
    unsigned long long best = mine;
    #pragma unroll
    for (int off=32; off>0; off>>=1){
      unsigned long long o = __shfl_xor(best, off, 64);
      best = (o < best) ? o : best;
    }
    if (mine == best) mine = ~0ull;
    if (lane == 0) nidx[q*16 + r] = (int)(unsigned)best;
  }
}

// ---------------- stats_a: [0,512) s1; [512,1536) t1act; [1536,1576) wl -> bf16 frag-swizzle ----------------
__global__ __launch_bounds__(256) void stats_a_kernel(const float* __restrict__ pos,
    const float4* __restrict__ pos4,
    const int* __restrict__ nidx,
    const float* __restrict__ w1a, const float* __restrict__ b1a,
    const float* __restrict__ w2,  const float* __restrict__ b2,
    const float* __restrict__ wl,  unsigned short* __restrict__ wlbf,
    float* __restrict__ tact,
    float* __restrict__ s1, float* __restrict__ s3){
  int tid = threadIdx.x;
  if (blockIdx.x < 512){
    __shared__ float relS[256][3];
    __shared__ float red[8][64];
    int r = blockIdx.x*256 + tid;
    int m = r >> 4;
    int j = nidx[r];
    if (pos4){
      float4 pj = pos4[j], pm = pos4[m];
      relS[tid][0] = pj.x-pm.x; relS[tid][1] = pj.y-pm.y; relS[tid][2] = pj.z-pm.z;
    } else {
      relS[tid][0] = pos[3*j  ]-pos[3*m  ];
      relS[tid][1] = pos[3*j+1]-pos[3*m+1];
      relS[tid][2] = pos[3*j+2]-pos[3*m+2];
    }
    __syncthreads();
    int c = tid & 31, g = tid >> 5;
    float w0=w1a[c], w1v=w1a[32+c], w2v=w1a[64+c], b=b1a[c];
    float s=0.f, q=0.f;
    for (int rr=g*32; rr<g*32+32; rr++){
      float h = elu(b + relS[rr][0]*w0 + relS[rr][1]*w1v + relS[rr][2]*w2v);
      s += h; q += h*h;
    }
    red[g][c]=s; red[g][32+c]=q;
    __syncthreads();
    if (tid < 64){
      float a=0.f;
      #pragma unroll
      for (int gg=0;gg<8;gg++) a += red[gg][tid];
      atomicAdd(&s1[tid], a);
    }
  } else if (blockIdx.x < 1536){
    __shared__ float relf[8][48];
    int m0 = (blockIdx.x-512)*8;
    if (pos4){
      for (int f = tid; f < 8*16; f += 256){
        int p = f >> 4, k = f & 15;
        int j = nidx[(m0+p)*16 + k];
        float4 pj = pos4[j], pm = pos4[m0+p];
        relf[p][k*3+0] = pj.x-pm.x;
        relf[p][k*3+1] = pj.y-pm.y;
        relf[p][k*3+2] = pj.z-pm.z;
      }
    } else {
      for (int f = tid; f < 8*48; f += 256){
        int p = f/48, kd = f%48, k = kd/3, d = kd%3;
        int j = nidx[(m0+p)*16 + k];
        relf[p][kd] = pos[3*j+d] - pos[3*(m0+p)+d];
      }
    }
    __syncthreads();
    float acc[8];
    #pragma unroll
    for (int p=0;p<8;p++) acc[p] = b2[tid];
    for (int kk=0; kk<48; kk++){
      float w = w2[kk*256 + tid];
      #pragma unroll
      for (int p=0;p<8;p++) acc[p] += relf[p][kk]*w;
    }
    float s=0.f, q=0.f;
    #pragma unroll
    for (int p=0;p<8;p++){
      float v = elu(acc[p]);
      s += v; q += v*v;
      tact[(size_t)(m0+p)*256 + tid] = v;
    }
    atomicAdd(&s3[tid], s); atomicAdd(&s3[256+tid], q);
  } else {
    // wl [320x256] f32 -> bf16, swizzled to MFMA B-fragment-linear order.
    int t = (blockIdx.x - 1536)*256 + tid;   // 0..10239
    int lane = t & 63;
    int fr   = t >> 6;
    int k0   = (fr >> 4)*32 + (lane >> 4)*8;
    int col  = (fr & 15)*16 + (lane & 15);
    const float* wp = wl + (size_t)k0*256 + col;
    uint4 v;
    v.x = cvt_pk_bf16(wp[0],    wp[256]);
    v.y = cvt_pk_bf16(wp[512],  wp[768]);
    v.z = cvt_pk_bf16(wp[1024], wp[1280]);
    v.w = cvt_pk_bf16(wp[1536], wp[1792]);
    ((uint4*)wlbf)[t] = v;
  }
}

// ---------------- stats_b: [0,1024) s2 (h2 stats, 128 rows/block, +h2 bf16 cache); [1024,2048) t2act ----------------
__global__ __launch_bounds__(256) void stats_b_kernel(const float* __restrict__ pos,
    const float4* __restrict__ pos4,
    const int* __restrict__ nidx,
    const float* __restrict__ w1a, const float* __restrict__ b1a,
    const float* __restrict__ s1,  const float* __restrict__ g1a, const float* __restrict__ be1a,
    const float* __restrict__ w1b, const float* __restrict__ b1b,
    float* __restrict__ tact,
    const float* __restrict__ s3,  const float* __restrict__ g2a, const float* __restrict__ be2a,
    const float* __restrict__ wc2a,const float* __restrict__ bc2a,
    unsigned short* __restrict__ h2c,
    float* __restrict__ s2, float* __restrict__ s4){
  int tid = threadIdx.x;
  const float invMK = 1.f/(float)MK;
  const float invM  = 1.f/8192.f;
  if (blockIdx.x < 1024){
    __shared__ float xnS[128][33];
    __shared__ float red[8][64];
    __shared__ float muA[32], ivA[32];
    if (tid < 32){
      float mu  = s1[tid]*invMK;
      float var = s1[32+tid]*invMK - mu*mu;
      muA[tid] = mu; ivA[tid] = rsqrtf(var+1e-5f)*g1a[tid];
    }
    __syncthreads();
    {
      int rl = tid >> 1;                    // 0..127
      int r  = blockIdx.x*128 + rl;
      int m = r >> 4;
      int j = nidx[r];
      float rx, ry, rz;
      if (pos4){
        float4 pj = pos4[j], pm = pos4[m];
        rx = pj.x-pm.x; ry = pj.y-pm.y; rz = pj.z-pm.z;
      } else {
        rx = pos[3*j]-pos[3*m]; ry = pos[3*j+1]-pos[3*m+1]; rz = pos[3*j+2]-pos[3*m+2];
      }
      int c0 = (tid & 1)*16;
      #pragma unroll
      for (int u=0; u<16; u++){
        int cc = c0 + u;
        float h = elu(b1a[cc] + rx*w1a[cc] + ry*w1a[32+cc] + rz*w1a[64+cc]);
        xnS[rl][cc] = (h-muA[cc])*ivA[cc] + be1a[cc];
      }
    }
    __syncthreads();
    int o = tid & 31, g = tid >> 5;
    float wcol[32];
    #pragma unroll
    for (int cc=0;cc<32;cc++) wcol[cc] = w1b[cc*32+o];
    float bo = b1b[o], s=0.f, q=0.f;
    for (int rr=g*16; rr<g*16+16; rr++){
      float a = bo;
      #pragma unroll
      for (int cc=0;cc<32;cc++) a += xnS[rr][cc]*wcol[cc];
      float v = elu(a);
      s += v; q += v*v;
      if (h2c) h2c[(size_t)(blockIdx.x*128 + rr)*32 + o] = f2bf(v);   // cache raw h2 (post-elu)
    }
    red[g][o]=s; red[g][32+o]=q;
    __syncthreads();
    if (tid < 64){
      float a=0.f;
      #pragma unroll
      for (int gg=0;gg<8;gg++) a += red[gg][tid];
      atomicAdd(&s2[tid], a);
    }
  } else {
    __shared__ float tn[8][256];
    int m0 = (blockIdx.x-1024)*8;
    float mu3  = s3[tid]*invM;
    float var3 = s3[256+tid]*invM - mu3*mu3;
    float i3   = rsqrtf(var3+1e-5f)*g2a[tid];
    float bb3  = be2a[tid];
    float tv[8];
    #pragma unroll
    for (int p=0;p<8;p++) tv[p] = tact[(size_t)(m0+p)*256 + tid];
    #pragma unroll
    for (int p=0;p<8;p++) tn[p][tid] = (tv[p]-mu3)*i3 + bb3;
    __syncthreads();
    int c = tid >> 4;
    float wreg[16];
    const float4* wv4 = (const float4*)(wc2a + tid*16);
    #pragma unroll
    for (int v=0; v<4; v++){ float4 f = wv4[v]; wreg[4*v]=f.x; wreg[4*v+1]=f.y; wreg[4*v+2]=f.z; wreg[4*v+3]=f.w; }
    float bias = bc2a[tid];
    float s=0.f, q=0.f;
    #pragma unroll
    for (int p=0;p<8;p++){
      float a2 = bias;
      #pragma unroll
      for (int l=0;l<16;l++) a2 += tn[p][c*16+l]*wreg[l];
      float v = elu(a2);
      s += v; q += v*v;
      tv[p] = v;
    }
    #pragma unroll
    for (int p=0;p<8;p++) tact[(size_t)(m0+p)*256 + tid] = tv[p];
    atomicAdd(&s4[tid], s); atomicAdd(&s4[256+tid], q);
  }
}

// ---------------- t3_stats: t3 = gconv2(BN(t2act)) (no elu) -> d_out + s5 ----------------
__global__ __launch_bounds__(256) void t3_stats_kernel(
    float* __restrict__ tact,
    const float* __restrict__ s4, const float* __restrict__ g2b, const float* __restrict__ be2b,
    const float* __restrict__ wc2b, const float* __restrict__ bc2b, float* __restrict__ s5){
  __shared__ float tn2[8][256];
  int m0 = blockIdx.x*8, tid = threadIdx.x;
  const float invM = 1.f/8192.f;
  float mu4  = s4[tid]*invM;
  float var4 = s4[256+tid]*invM - mu4*mu4;
  float i4   = rsqrtf(var4+1e-5f)*g2b[tid];
  float bb4  = be2b[tid];
  float tv[8];
  #pragma unroll
  for (int p=0;p<8;p++) tv[p] = tact[(size_t)(m0+p)*256 + tid];
  #pragma unroll
  for (int p=0;p<8;p++) tn2[p][tid] = (tv[p]-mu4)*i4 + bb4;
  __syncthreads();
  int c = tid >> 4;
  float w2reg[16];
  { const float4* wv4 = (const float4*)(wc2b + tid*16);
    #pragma unroll
    for (int v=0; v<4; v++){ float4 f = wv4[v]; w2reg[4*v]=f.x; w2reg[4*v+1]=f.y; w2reg[4*v+2]=f.z; w2reg[4*v+3]=f.w; } }
  float bias2 = bc2b[tid];
  float s=0.f, q=0.f;
  #pragma unroll
  for (int p=0;p<8;p++){
    float a3 = bias2;
    #pragma unroll
    for (int l=0;l<16;l++) a3 += tn2[p][c*16+l]*w2reg[l];
    s += a3; q += a3*a3;
    tv[p] = a3;
  }
  #pragma unroll
  for (int p=0;p<8;p++) tact[(size_t)(m0+p)*256 + tid] = tv[p];
  atomicAdd(&s5[tid], s); atomicAdd(&s5[256+tid], q);
}

// ---------------- final (MFMA path): PF=4, 19KB LDS, 8 blocks/CU; phase A loads cached h2 if avail ----------------
#define PFM 4
__global__ __launch_bounds__(256) void final_mfma_kernel(
    const float* __restrict__ x, const float* __restrict__ pos,
    const float4* __restrict__ pos4, const int* __restrict__ nidx,
    const float* __restrict__ w1a, const float* __restrict__ b1a,
    const float* __restrict__ g1a, const float* __restrict__ be1a,
    const float* __restrict__ w1b, const float* __restrict__ b1b,
    const float* __restrict__ g1b, const float* __restrict__ be1b,
    const float* __restrict__ g2c, const float* __restrict__ be2c,
    const float* __restrict__ wcd, const float* __restrict__ bcd,
    const unsigned short* __restrict__ wlbf, const float* __restrict__ bl,
    const unsigned short* __restrict__ h2c,
    const float* __restrict__ st,
    float* __restrict__ out){
  __shared__ float tA[PFM][256];                // BN(t3), f32 (4KB)
  __shared__ unsigned short xs[PFM*32*17];      // h2n bf16 (4.4KB)
  __shared__ unsigned short yh[16][328];        // yy bf16; rows 4..15 zero (MFMA M-pad)
  __shared__ int   sidx[PFM*16];
  __shared__ float mu1[32], i1g[32], mu2[32], i2g[32];
  int tid = threadIdx.x;
  int m0  = blockIdx.x*PFM;
  const float invMK = 1.f/(float)MK;
  const float invM  = 1.f/8192.f;

  if (tid < PFM*16) sidx[tid] = nidx[m0*16 + tid];
  if (tid < 32){
    float mu  = st[tid]*invMK;
    float var = st[32+tid]*invMK - mu*mu;
    mu1[tid] = mu; i1g[tid] = rsqrtf(var+1e-5f)*g1a[tid];
    float mu_2  = st[64+tid]*invMK;
    float var_2 = st[96+tid]*invMK - mu_2*mu_2;
    mu2[tid] = mu_2; i2g[tid] = rsqrtf(var_2+1e-5f)*g1b[tid];
  }
  {
    unsigned short* yz = &yh[PFM][0];
    for (int i = tid; i < (16-PFM)*328; i += 256) yz[i] = 0;
  }
  {
    float mu5 = st[1152+tid]*invM, var5 = st[1408+tid]*invM - mu5*mu5;
    float i5 = rsqrtf(var5+1e-5f)*g2c[tid], bb5 = be2c[tid];
    #pragma unroll
    for (int p=0;p<PFM;p++){
      float v = out[(size_t)(m0+p)*256 + tid];
      tA[p][tid] = (v-mu5)*i5 + bb5;
    }
  }
  __syncthreads();

  // phase A: h2n for 64 neighbor rows (4 threads/row).
  // Fast path: load cached h2 (bf16, written by stats_b) and apply BN only.
  {
    int row = tid >> 2;
    int p = row >> 4, k = row & 15;
    int q8 = (tid & 3)*8;
    if (h2c){
      size_t r = (size_t)blockIdx.x*64 + row;
      uint4 hv = *(const uint4*)(h2c + r*32 + q8);     // 8 bf16, 16B aligned
      unsigned dw[4] = {hv.x, hv.y, hv.z, hv.w};
      #pragma unroll
      for (int d=0; d<4; ++d){
        int o0 = q8 + 2*d, o1 = o0 + 1;
        float v0 = __uint_as_float(dw[d] << 16);
        float v1 = __uint_as_float(dw[d] & 0xFFFF0000u);
        xs[(p*32 + o0)*17 + k] = f2bf((v0-mu2[o0])*i2g[o0] + be1b[o0]);
        xs[(p*32 + o1)*17 + k] = f2bf((v1-mu2[o1])*i2g[o1] + be1b[o1]);
      }
    } else {
      int m = m0 + p;
      int j = sidx[row];
      float rx, ry, rz;
      if (pos4){
        float4 pj = pos4[j], pm = pos4[m];
        rx = pj.x-pm.x; ry = pj.y-pm.y; rz = pj.z-pm.z;
      } else {
        rx = pos[3*j]-pos[3*m]; ry = pos[3*j+1]-pos[3*m+1]; rz = pos[3*j+2]-pos[3*m+2];
      }
      float xn[32];
      #pragma unroll
      for (int cc=0; cc<32; cc++){
        float h = elu(b1a[cc] + rx*w1a[cc] + ry*w1a[32+cc] + rz*w1a[64+cc]);
        xn[cc] = (h-mu1[cc])*i1g[cc] + be1a[cc];
      }
      #pragma unroll
      for (int oo=0; oo<8; oo++){
        int o = q8 + oo;
        float a = b1b[o];
        #pragma unroll
        for (int cc=0; cc<32; cc++) a += xn[cc]*w1b[cc*32+o];
        float h2v = elu(a);
        xs[(p*32 + o)*17 + k] = f2bf((h2v-mu2[o])*i2g[o] + be1b[o]);
      }
    }
  }
  __syncthreads();

  // phase B: X-transform + depthwise -> yy (bf16 into yh); x gathered direct (L2-resident, 4MB)
  for (int pair = tid; pair < PFM*160; pair += 256){
    int p = pair / 160, cch = pair % 160;
    float av[16];
    if (cch < 32){
      #pragma unroll
      for (int k16=0;k16<16;k16++)
        av[k16] = __uint_as_float((unsigned)xs[(p*32+cch)*17 + k16] << 16);
    } else {
      #pragma unroll
      for (int k16=0;k16<16;k16++) av[k16] = x[(size_t)sidx[p*16+k16]*128 + (cch-32)];
    }
    float xt[16];
    #pragma unroll
    for (int j16=0;j16<16;j16++) xt[j16]=0.f;
    #pragma unroll
    for (int k16=0;k16<16;k16++){
      float a = av[k16];
      #pragma unroll
      for (int j16=0;j16<16;j16++) xt[j16] += a*tA[p][k16*16+j16];
    }
    float y0 = bcd[cch*2], y1 = bcd[cch*2+1];
    #pragma unroll
    for (int l=0;l<16;l++){
      y0 += xt[l]*wcd[cch*32 + l];
      y1 += xt[l]*wcd[cch*32 + 16 + l];
    }
    *(unsigned*)&yh[p][cch*2] = cvt_pk_bf16(y0, y1);
  }
  __syncthreads();

  // phase C: out[4x256] = yy[4(->16)x320] @ wl[320x256] + bl via MFMA 16x16x32 bf16.
  {
    int lane = tid & 63;
    int wvi  = tid >> 6;
    int lrow = lane & 15;
    int lgrp = lane >> 4;
    const bf16x8* wb = (const bf16x8*)wlbf;
    f32x4 acc[4];
    #pragma unroll
    for (int nt=0; nt<4; ++nt) acc[nt] = (f32x4){0.f,0.f,0.f,0.f};
    #pragma unroll 1
    for (int kt = 0; kt < 10; ++kt){
      bf16x8 ah = *(const bf16x8*)&yh[lrow][kt*32 + lgrp*8];
      #pragma unroll
      for (int nt = 0; nt < 4; ++nt){
        bf16x8 bh = wb[(size_t)((kt*16 + wvi*4 + nt)*64) + lane];
        acc[nt] = __builtin_amdgcn_mfma_f32_16x16x32_bf16(ah, bh, acc[nt], 0, 0, 0);
      }
    }
    if (lgrp == 0){
      #pragma unroll
      for (int nt=0; nt<4; ++nt){
        int col = wvi*64 + nt*16 + lrow;
        float bv = bl[col];
        #pragma unroll
        for (int r=0;r<4;r++){
          int orow = r;                        // D row = (lane>>4)*4 + reg; rows 0..3 live (m89-verified)
          out[(size_t)(m0+orow)*256 + col] = acc[nt][r] + bv;
        }
      }
    }
  }
}

// ---------------- final (legacy fallback, verbatim R3): PF=4, serial phase C ----------------
#define PF 4
__global__ __launch_bounds__(256) void final_kernel(
    const float* __restrict__ x, const float* __restrict__ pos, const int* __restrict__ nidx,
    const float* __restrict__ w1a, const float* __restrict__ b1a,
    const float* __restrict__ g1a, const float* __restrict__ be1a,
    const float* __restrict__ w1b, const float* __restrict__ b1b,
    const float* __restrict__ g1b, const float* __restrict__ be1b,
    const float* __restrict__ g2c, const float* __restrict__ be2c,
    const float* __restrict__ wcd, const float* __restrict__ bcd,
    const float* __restrict__ wl,  const float* __restrict__ bl,
    const float* __restrict__ st,
    float* __restrict__ out){
  __shared__ float tA[PF][256];
  __shared__ float xs[PF*32*17];
  __shared__ float yy[PF][320];
  __shared__ int   sidx[PF*16];
  __shared__ float mu1[32], i1g[32], mu2[32], i2g[32];
  int tid = threadIdx.x;
  int m0  = blockIdx.x*PF;
  const float invMK = 1.f/(float)MK;
  const float invM  = 1.f/8192.f;

  if (tid < PF*16) sidx[tid] = nidx[m0*16 + tid];
  if (tid < 32){
    float mu  = st[tid]*invMK;
    float var = st[32+tid]*invMK - mu*mu;
    mu1[tid] = mu; i1g[tid] = rsqrtf(var+1e-5f)*g1a[tid];
    float mu_2  = st[64+tid]*invMK;
    float var_2 = st[96+tid]*invMK - mu_2*mu_2;
    mu2[tid] = mu_2; i2g[tid] = rsqrtf(var_2+1e-5f)*g1b[tid];
  }
  {
    float mu5 = st[1152+tid]*invM, var5 = st[1408+tid]*invM - mu5*mu5;
    float i5 = rsqrtf(var5+1e-5f)*g2c[tid], bb5 = be2c[tid];
    #pragma unroll
    for (int p=0;p<PF;p++){
      float v = out[(size_t)(m0+p)*256 + tid];
      tA[p][tid] = (v-mu5)*i5 + bb5;
    }
  }
  __syncthreads();

  {
    int row = tid >> 2;
    int p = row >> 4, k = row & 15;
    int q8 = (tid & 3)*8;
    int m = m0 + p;
    int j = sidx[p*16 + k];
    float rx = pos[3*j]-pos[3*m], ry = pos[3*j+1]-pos[3*m+1], rz = pos[3*j+2]-pos[3*m+2];
    float xn[32];
    #pragma unroll
    for (int cc=0; cc<32; cc++){
      float h = elu(b1a[cc] + rx*w1a[cc] + ry*w1a[32+cc] + rz*w1a[64+cc]);
      xn[cc] = (h-mu1[cc])*i1g[cc] + be1a[cc];
    }
    #pragma unroll
    for (int oo=0; oo<8; oo++){
      int o = q8 + oo;
      float a = b1b[o];
      #pragma unroll
      for (int cc=0; cc<32; cc++) a += xn[cc]*w1b[cc*32+o];
      float h2v = elu(a);
      xs[(p*32 + o)*17 + k] = (h2v-mu2[o])*i2g[o] + be1b[o];
    }
  }
  __syncthreads();

  for (int pair = tid; pair < PF*160; pair += 256){
    int p = pair / 160, cch = pair % 160;
    float av[16];
    if (cch < 32){
      #pragma unroll
      for (int k16=0;k16<16;k16++) av[k16] = xs[(p*32+cch)*17 + k16];
    } else {
      #pragma unroll
      for (int k16=0;k16<16;k16++) av[k16] = x[(size_t)sidx[p*16+k16]*128 + (cch-32)];
    }
    float xt[16];
    #pragma unroll
    for (int j16=0;j16<16;j16++) xt[j16]=0.f;
    #pragma unroll
    for (int k16=0;k16<16;k16++){
      float a = av[k16];
      #pragma unroll
      for (int j16=0;j16<16;j16++) xt[j16] += a*tA[p][k16*16+j16];
    }
    float y0 = bcd[cch*2], y1 = bcd[cch*2+1];
    #pragma unroll
    for (int l=0;l<16;l++){
      y0 += xt[l]*wcd[cch*32 + l];
      y1 += xt[l]*wcd[cch*32 + 16 + l];
    }
    yy[p][cch*2] = y0; yy[p][cch*2+1] = y1;
  }
  __syncthreads();

  float accO[PF];
  #pragma unroll
  for (int p=0;p<PF;p++) accO[p] = bl[tid];
  for (int q=0;q<320;q++){
    float w = wl[q*256 + tid];
    #pragma unroll
    for (int p=0;p<PF;p++) accO[p] += yy[p][q]*w;
  }
  #pragma unroll
  for (int p=0;p<PF;p++) out[(size_t)(m0+p)*256 + tid] = accO[p];
}

extern "C" void kernel_launch(void* const* d_in, const int* in_sizes, int n_in,
                              void* d_out, int out_size, void* d_ws, size_t ws_size,
                              hipStream_t stream){
  const float* x    = (const float*)d_in[0];
  const float* pos  = (const float*)d_in[1];
  const float* w1a  = (const float*)d_in[2];
  const float* b1a  = (const float*)d_in[3];
  const float* g1a  = (const float*)d_in[4];
  const float* be1a = (const float*)d_in[5];
  const float* w1b  = (const float*)d_in[6];
  const float* b1b  = (const float*)d_in[7];
  const float* g1b  = (const float*)d_in[8];
  const float* be1b = (const float*)d_in[9];
  const float* w2   = (const float*)d_in[10];
  const float* b2   = (const float*)d_in[11];
  const float* g2a  = (const float*)d_in[12];
  const float* be2a = (const float*)d_in[13];
  const float* wc2a = (const float*)d_in[14];
  const float* bc2a = (const float*)d_in[15];
  const float* g2b  = (const float*)d_in[16];
  const float* be2b = (const float*)d_in[17];
  const float* wc2b = (const float*)d_in[18];
  const float* bc2b = (const float*)d_in[19];
  const float* g2c  = (const float*)d_in[20];
  const float* be2c = (const float*)d_in[21];
  const float* wcd  = (const float*)d_in[22];
  const float* bcd  = (const float*)d_in[23];
  const float* wl   = (const float*)d_in[24];
  const float* bl   = (const float*)d_in[25];
  float* out = (float*)d_out;

  char* ws = (char*)d_ws;
  int*   nidx = (int*)(ws + 0);          // 512 KB
  float* st   = (float*)(ws + 524288);   // 8 KB (s1@0, s2@64, s3@128, s4@640, s5@1152)
  float* s1 = st;
  float* s2 = st + 64;
  float* s3 = st + 128;
  float* s4 = st + 640;
  float* s5 = st + 1152;
  bool big  = ws_size >= (size_t)696320;
  bool big2 = ws_size >= (size_t)824320;
  bool big3 = ws_size >= (size_t)9212928;
  unsigned short* wlbf = big  ? (unsigned short*)(ws + 532480) : (unsigned short*)0;  // 160 KB
  float4*         pos4 = big2 ? (float4*)(ws + 696320)         : (float4*)0;          // 128 KB
  unsigned short* h2c  = big3 ? (unsigned short*)(ws + 824320) : (unsigned short*)0;  // 8 MB

  knn_kernel<<<1024,512,0,stream>>>(pos, nidx, st, pos4);
  stats_a_kernel<<<(big ? 1576 : 1536),256,0,stream>>>(pos, pos4, nidx, w1a, b1a, w2, b2,
                                                       wl, wlbf, out, s1, s3);
  stats_b_kernel<<<2048,256,0,stream>>>(pos, pos4, nidx, w1a, b1a, s1, g1a, be1a, w1b, b1b,
                                        out, s3, g2a, be2a, wc2a, bc2a, h2c, s2, s4);
  t3_stats_kernel<<<1024,256,0,stream>>>(out, s4, g2b, be2b, wc2b, bc2b, s5);
  if (big){
    final_mfma_kernel<<<2048,256,0,stream>>>(x, pos, pos4, nidx,
                                             w1a, b1a, g1a, be1a, w1b, b1b, g1b, be1b,
                                             g2c, be2c, wcd, bcd, wlbf, bl, h2c, st, out);
  } else {
    final_kernel<<<2048,256,0,stream>>>(x, pos, nidx,
                                        w1a, b1a, g1a, be1a, w1b, b1b, g1b, be1b,
                                        g2c, be2c, wcd, bcd, wl, bl, st, out);
  }
}